// Round 4
// baseline (66.002 us; speedup 1.0000x reference)
//
#include <hip/hip_runtime.h>
#include <hip/hip_bf16.h>

#define B_ 2048
#define D_ 17
#define H_ 8
#define HID_ 256
#define OUT_ 23
#define XROW 8721       /* 513*17 floats per batch */

__device__ __forceinline__ float4 ld4u(const float* p) {   // 4B-aligned 16B load
  float4 v; __builtin_memcpy(&v, p, 16); return v;
}

// ---------------- Kernel 1: register-streaming attention -> comb (B x 26) ----------------
// Block 512 = 8 waves = 4 batches (2 waves/batch, row-halves). No LDS staging:
// lane = (head = l&7, rowgroup = l>>3); 8 head-lanes share each row's global
// reads (same-address coalescing); online no-max softmax in registers;
// shfl_xor reduce over rowgroups; tiny LDS only for the final combine.
__global__ __launch_bounds__(512, 4) void attn_comb_kernel(
    const float* __restrict__ x,
    const float* __restrict__ Wk, const float* __restrict__ bk,
    const float* __restrict__ Wv, const float* __restrict__ bv,
    const float* __restrict__ q,
    const float* __restrict__ Wo, const float* __restrict__ bo,
    float* __restrict__ comb)
{
  __shared__ float s_qk[H_][20];          // padded
  __shared__ float s_ch[H_];
  __shared__ float s_part[8][H_][18];     // per-wave per-head (den, acc[17])
  __shared__ float s_swn[4][H_][D_];
  __shared__ float s_agg[4][H_ * D_];
  __shared__ float s_wp[4][136];

  const int t = threadIdx.x;

  // ---- phase 0: fold q into Wk (once per block)
  if (t < H_ * D_) {
    const int h = t / D_, dd = t - h * D_;
    float s = 0.f;
    #pragma unroll
    for (int e = 0; e < D_; ++e) s = fmaf(Wk[h*289 + e*D_ + dd], q[h*D_ + e], s);
    s_qk[h][dd] = s;
  }
  if (t < H_) {
    float s = 0.f;
    #pragma unroll
    for (int e = 0; e < D_; ++e) s = fmaf(bk[t*D_ + e], q[t*D_ + e], s);
    s_ch[t] = s;
  }
  __syncthreads();

  const int w    = t >> 6;          // wave 0..7
  const int lane = t & 63;
  const int bb   = w >> 1;          // batch within block
  const int hb   = w & 1;           // row half (0: rows 0-255, 1: 256-511)
  const int h    = lane & 7;
  const int rg   = lane >> 3;       // rowgroup 0..7
  const int b    = blockIdx.x * 4 + bb;

  float qkr[D_];
  #pragma unroll
  for (int d = 0; d < D_; ++d) qkr[d] = s_qk[h][d];
  const float chr = s_ch[h];

  const float* rbase = x + (size_t)b * XROW + D_ + (size_t)(rg + (hb << 8)) * D_;

  float den = 0.f;
  float acc[D_];
  #pragma unroll
  for (int d = 0; d < D_; ++d) acc[d] = 0.f;

  // ---- main loop: 32 steps (8 rows/step across rowgroups), unroll 4
  for (int s = 0; s < 32; s += 4) {
    float4 va[4][4]; float vb[4];
    #pragma unroll
    for (int j = 0; j < 4; ++j) {
      const float* rp = rbase + (size_t)(s + j) * 136;   // 8 rows * 17
      va[j][0] = ld4u(rp);      va[j][1] = ld4u(rp + 4);
      va[j][2] = ld4u(rp + 8);  va[j][3] = ld4u(rp + 12);
      vb[j] = rp[16];
    }
    #pragma unroll
    for (int j = 0; j < 4; ++j) {
      float sc = chr;
      #pragma unroll
      for (int k = 0; k < 4; ++k) {
        sc = fmaf(qkr[4*k+0], va[j][k].x, sc);
        sc = fmaf(qkr[4*k+1], va[j][k].y, sc);
        sc = fmaf(qkr[4*k+2], va[j][k].z, sc);
        sc = fmaf(qkr[4*k+3], va[j][k].w, sc);
      }
      sc = fmaf(qkr[16], vb[j], sc);
      // masked rows are exact zeros -> word0 == 0 (live word0==0 has P~1e-45)
      const float p = (va[j][0].x != 0.f) ? __expf(sc) : 0.f;
      den += p;
      #pragma unroll
      for (int k = 0; k < 4; ++k) {
        acc[4*k+0] = fmaf(p, va[j][k].x, acc[4*k+0]);
        acc[4*k+1] = fmaf(p, va[j][k].y, acc[4*k+1]);
        acc[4*k+2] = fmaf(p, va[j][k].z, acc[4*k+2]);
        acc[4*k+3] = fmaf(p, va[j][k].w, acc[4*k+3]);
      }
      acc[16] = fmaf(p, vb[j], acc[16]);
    }
  }

  // ---- in-wave reduce over rowgroups (lanes with same head)
  #pragma unroll
  for (int m = 8; m <= 32; m <<= 1) {
    den += __shfl_xor(den, m, 64);
    #pragma unroll
    for (int d = 0; d < D_; ++d) acc[d] += __shfl_xor(acc[d], m, 64);
  }
  if (lane < 8) {
    s_part[w][lane][0] = den;
    #pragma unroll
    for (int d = 0; d < D_; ++d) s_part[w][lane][1 + d] = acc[d];
  }
  __syncthreads();

  // ---- per-batch finish: threads [bb*128, bb*128+128)
  const int u0 = t & 127;
  for (int u = u0; u < 136; u += 128) {          // swn[h][d] = acc/den (combine halves)
    const int hh = u / D_, d = u - hh * D_;
    const float dn = s_part[2*bb][hh][0] + s_part[2*bb+1][hh][0];
    const float ac = s_part[2*bb][hh][1+d] + s_part[2*bb+1][hh][1+d];
    s_swn[bb][hh][d] = ac / dn;
  }
  __syncthreads();
  for (int u = u0; u < 136; u += 128) {          // agg = bv + Wv·swn
    const int hh = u / D_, e = u - hh * D_;
    float s = bv[hh*D_ + e];
    #pragma unroll
    for (int d = 0; d < D_; ++d) s = fmaf(Wv[hh*289 + e*D_ + d], s_swn[bb][hh][d], s);
    s_agg[bb][hh*D_ + e] = s;
  }
  __syncthreads();
  for (int u = u0; u < 136; u += 128) {          // Wo partials: 17 outs x 8 parts
    const int o = u >> 3, pt = u & 7;
    float s = 0.f;
    #pragma unroll
    for (int j = 0; j < D_; ++j) s = fmaf(Wo[o*136 + pt*D_ + j], s_agg[bb][pt*D_ + j], s);
    s_wp[bb][u] = s;
  }
  __syncthreads();
  if (u0 < D_) {
    float s = bo[u0];
    #pragma unroll
    for (int pt = 0; pt < 8; ++pt) s += s_wp[bb][u0*8 + pt];
    comb[b*26 + u0] = s;
  } else if (u0 < 26) {
    comb[b*26 + u0] = x[(size_t)b * XROW + (u0 - D_)];   // special
  }
}

// ---------------- Kernel 2: LDS-tiled transpose of the two 256x256 W2 ----------------
__global__ __launch_bounds__(256) void transpose_w2_kernel(
    const float* __restrict__ pW2, const float* __restrict__ vW2,
    float* __restrict__ pW2t, float* __restrict__ vW2t)
{
  __shared__ float tile[32][33];
  const int bid = blockIdx.x;           // 128 blocks = 2 matrices x 64 tiles
  const int m = bid >> 6, tid = bid & 63;
  const int ti = (tid >> 3) * 32, tk = (tid & 7) * 32;
  const float* src = m ? vW2 : pW2;
  float* dst = m ? vW2t : pW2t;
  const int tx = threadIdx.x & 31, ty = threadIdx.x >> 5;
  #pragma unroll
  for (int r = 0; r < 4; ++r) tile[ty + 8*r][tx] = src[(ti + ty + 8*r)*HID_ + tk + tx];
  __syncthreads();
  #pragma unroll
  for (int r = 0; r < 4; ++r) dst[(tk + ty + 8*r)*HID_ + ti + tx] = tile[tx][ty + 8*r];
}

// ---------------- Kernel 3: fused policy+value MLPs ----------------
// Grid 256 x 512 threads; 8 batches/block -> W2 traffic 4x lower than R3.
// t = p*256 + i: thread owns output i of MLP p for all 8 batches.
__global__ __launch_bounds__(512) void mlp_kernel(
    const float* __restrict__ comb,
    const float* __restrict__ pW1, const float* __restrict__ pb1,
    const float* __restrict__ pW2t, const float* __restrict__ pb2,
    const float* __restrict__ pW3, const float* __restrict__ pb3,
    const float* __restrict__ vW1, const float* __restrict__ vb1,
    const float* __restrict__ vW2t, const float* __restrict__ vb2,
    const float* __restrict__ vW3, const float* __restrict__ vb3,
    float* __restrict__ out)
{
  __shared__ float s_comb[8][26];
  __shared__ __align__(16) float s_h1[2][8][HID_];
  __shared__ __align__(16) float s_h2[2][8][HID_];

  const int t = threadIdx.x;
  const int b0 = blockIdx.x * 8;
  const int p = t >> 8;
  const int i = t & 255;

  if (t < 208) { int bb = t / 26, k = t - bb*26; s_comb[bb][k] = comb[(size_t)(b0 + bb)*26 + k]; }
  __syncthreads();

  const float* W1  = p ? vW1  : pW1;   const float* B1 = p ? vb1 : pb1;
  const float* W2t = p ? vW2t : pW2t;  const float* B2 = p ? vb2 : pb2;

  // ---- layer 1: 26 -> 256
  {
    float a[8];
    #pragma unroll
    for (int bb = 0; bb < 8; ++bb) a[bb] = 0.f;
    const float* wr = W1 + i*26;
    for (int k = 0; k < 26; ++k) {
      const float wk = wr[k];
      #pragma unroll
      for (int bb = 0; bb < 8; ++bb) a[bb] = fmaf(wk, s_comb[bb][k], a[bb]);
    }
    const float bias = B1[i];
    #pragma unroll
    for (int bb = 0; bb < 8; ++bb) s_h1[p][bb][i] = fmaxf(a[bb] + bias, 0.f);
  }
  __syncthreads();

  // ---- layer 2: 256 -> 256 (coalesced transposed weights, broadcast LDS h)
  {
    float a[8];
    #pragma unroll
    for (int bb = 0; bb < 8; ++bb) a[bb] = 0.f;
    #pragma unroll 2
    for (int k4 = 0; k4 < 64; ++k4) {
      const int k = 4*k4;
      const float w0 = W2t[(k    )*HID_ + i];
      const float w1 = W2t[(k + 1)*HID_ + i];
      const float w2 = W2t[(k + 2)*HID_ + i];
      const float w3 = W2t[(k + 3)*HID_ + i];
      #pragma unroll
      for (int bb = 0; bb < 8; ++bb) {
        const float4 hv = *(const float4*)&s_h1[p][bb][k];   // wave-uniform broadcast
        a[bb] = fmaf(w0, hv.x, fmaf(w1, hv.y, fmaf(w2, hv.z, fmaf(w3, hv.w, a[bb]))));
      }
    }
    const float bias = B2[i];
    #pragma unroll
    for (int bb = 0; bb < 8; ++bb) s_h2[p][bb][i] = fmaxf(a[bb] + bias, 0.f);
  }
  __syncthreads();

  // ---- layer 3
  if (t < 184) {                        // policy: 8 batches x 23 outputs
    const int bb = t / OUT_, o = t - bb * OUT_;
    const float4* w4 = (const float4*)(pW3 + o * HID_);
    const float4* h4 = (const float4*)&s_h2[0][bb][0];
    float s = pb3[o];
    for (int k = 0; k < 64; ++k) {
      const float4 wv = w4[k], hv = h4[k];
      s = fmaf(wv.x, hv.x, fmaf(wv.y, hv.y, fmaf(wv.z, hv.z, fmaf(wv.w, hv.w, s))));
    }
    out[(size_t)(b0 + bb) * OUT_ + o] = s;
  } else if (t >= 256 && t < 264) {     // value: 8 batches x 1 output
    const int bb = t - 256;
    const float4* w4 = (const float4*)vW3;
    const float4* h4 = (const float4*)&s_h2[1][bb][0];
    float s = vb3[0];
    for (int k = 0; k < 64; ++k) {
      const float4 wv = w4[k], hv = h4[k];
      s = fmaf(wv.x, hv.x, fmaf(wv.y, hv.y, fmaf(wv.z, hv.z, fmaf(wv.w, hv.w, s))));
    }
    out[(size_t)B_ * OUT_ + b0 + bb] = s;
  }
}

extern "C" void kernel_launch(void* const* d_in, const int* in_sizes, int n_in,
                              void* d_out, int out_size, void* d_ws, size_t ws_size,
                              hipStream_t stream) {
  (void)in_sizes; (void)n_in; (void)out_size; (void)ws_size;
  const float* x   = (const float*)d_in[0];
  const float* Wk  = (const float*)d_in[1];
  const float* bk  = (const float*)d_in[2];
  const float* Wv  = (const float*)d_in[3];
  const float* bv  = (const float*)d_in[4];
  const float* q   = (const float*)d_in[5];
  const float* Wo  = (const float*)d_in[6];
  const float* bo  = (const float*)d_in[7];
  const float* pW1 = (const float*)d_in[8];
  const float* pb1 = (const float*)d_in[9];
  const float* pW2 = (const float*)d_in[10];
  const float* pb2 = (const float*)d_in[11];
  const float* pW3 = (const float*)d_in[12];
  const float* pb3 = (const float*)d_in[13];
  const float* vW1 = (const float*)d_in[14];
  const float* vb1 = (const float*)d_in[15];
  const float* vW2 = (const float*)d_in[16];
  const float* vb2 = (const float*)d_in[17];
  const float* vW3 = (const float*)d_in[18];
  const float* vb3 = (const float*)d_in[19];
  float* out = (float*)d_out;

  // workspace: comb (2048*26) | pW2t (65536) | vW2t (65536) floats
  float* comb = (float*)d_ws;
  float* pW2t = comb + (size_t)B_ * 26;
  float* vW2t = pW2t + (size_t)HID_ * HID_;

  transpose_w2_kernel<<<128, 256, 0, stream>>>(pW2, vW2, pW2t, vW2t);
  attn_comb_kernel<<<B_ / 4, 512, 0, stream>>>(x, Wk, bk, Wv, bv, q, Wo, bo, comb);
  mlp_kernel<<<B_ / 8, 512, 0, stream>>>(comb, pW1, pb1, pW2t, pb2, pW3, pb3,
                                         vW1, vb1, vW2t, vb2, vW3, vb3, out);
}